// Round 1
// baseline (605.949 us; speedup 1.0000x reference)
//
#include <hip/hip_runtime.h>
#include <stdint.h>

// MHATokenNoLayerNorm on MI355X (gfx950).
// Strategy: fp32 -> (bf16 hi, bf16 lo) split everywhere; every GEMM-shaped op
// uses mfma_f32_16x16x32_bf16 with 3-term split product (hi*hi + hi*lo + lo*hi)
// => ~1e-4 relative error vs fp32 reference.
// Pipeline:
//   split(ini_q), split(ini_k), splitT(Wq/Wkv/Wo)
//   gemm<split-out>: q  = ini_q @ Wq      (512 x 768 x 768)
//   gemm<split-out>: kv = ini_k @ Wkv     (32768 x 768 x 768)
//   attn: per (b,h,s): S=Q Kv^T, softmax over t, O = P Kv  -> res hi/lo
//   gemm<f32+bias>:  out = res @ Wo + bo  (32768 x 768 x 768)
// Workspace: ~211.6 MB (res reuses the ini_k split buffers).

typedef __bf16 bf16_t;
typedef __attribute__((ext_vector_type(8))) __bf16 bf16x8;
typedef __attribute__((ext_vector_type(4))) __bf16 bf16x4;
typedef __attribute__((ext_vector_type(4))) float f32x4;

#define HDIM 768

// ---------------- split kernels ----------------
__global__ __launch_bounds__(256) void split4_kernel(const float* __restrict__ x,
                                                     bf16_t* __restrict__ h,
                                                     bf16_t* __restrict__ l) {
  int i = blockIdx.x * 256 + threadIdx.x;
  const float4 v = ((const float4*)x)[i];
  float vv[4] = {v.x, v.y, v.z, v.w};
  bf16x4 hv, lv;
#pragma unroll
  for (int e = 0; e < 4; ++e) {
    bf16_t hb = (bf16_t)vv[e];
    hv[e] = hb;
    lv[e] = (bf16_t)(vv[e] - (float)hb);
  }
  ((bf16x4*)h)[i] = hv;
  ((bf16x4*)l)[i] = lv;
}

// W[768][768] -> WT_hi/WT_lo[768][768]  (row n of WT = column n of W)
__global__ __launch_bounds__(256) void splitT_kernel(const float* __restrict__ w,
                                                     bf16_t* __restrict__ hT,
                                                     bf16_t* __restrict__ lT) {
  int idx = blockIdx.x * 256 + threadIdx.x;  // 589824 threads
  int k = idx / HDIM, n = idx % HDIM;
  float v = w[idx];
  bf16_t hb = (bf16_t)v;
  hT[n * HDIM + k] = hb;
  lT[n * HDIM + k] = (bf16_t)(v - (float)hb);
}

// ---------------- split-bf16 GEMM ----------------
// C[M,768] = A[M,768] @ W[768,768]; W passed transposed (WT[n][k]).
// 128x128 tile, BK=32, 4 waves (each 64x64), LDS padded to 40 bf16/row
// (80B stride -> 2-way bank aliasing on ds_read_b128 = free).
// EPI 0: write C as bf16 hi/lo pair. EPI 1: write f32 + bias.
template <int EPI>
__global__ __launch_bounds__(256) void gemm_kernel(
    const bf16_t* __restrict__ Agh, const bf16_t* __restrict__ Agl,
    const bf16_t* __restrict__ Bgh, const bf16_t* __restrict__ Bgl,
    bf16_t* __restrict__ Ch, bf16_t* __restrict__ Cl,
    float* __restrict__ Cf, const float* __restrict__ bias) {
  const int LDT = 40;
  __shared__ bf16_t sAh[128 * 40], sAl[128 * 40], sBh[128 * 40], sBl[128 * 40];
  const int bn = blockIdx.x, bm = blockIdx.y;  // bn fastest: 6 blocks share A tile in L2
  const int tid = threadIdx.x;
  const int lane = tid & 63;
  const int w = tid >> 6;
  const int wr = (w >> 1) * 64, wc = (w & 1) * 64;
  const int l15 = lane & 15, l4 = lane >> 4;
  f32x4 acc[4][4] = {};

  for (int kt = 0; kt < 24; ++kt) {
    const int k0 = kt * 32;
    __syncthreads();
#pragma unroll
    for (int j = 0; j < 2; ++j) {
      int c = tid + j * 256;  // 512 chunks of 8 bf16
      int row = c >> 2, cg = c & 3;
      size_t ga = (size_t)(bm * 128 + row) * HDIM + k0 + cg * 8;
      size_t gb = (size_t)(bn * 128 + row) * HDIM + k0 + cg * 8;
      int lo = row * LDT + cg * 8;
      *(bf16x8*)&sAh[lo] = *(const bf16x8*)&Agh[ga];
      *(bf16x8*)&sAl[lo] = *(const bf16x8*)&Agl[ga];
      *(bf16x8*)&sBh[lo] = *(const bf16x8*)&Bgh[gb];
      *(bf16x8*)&sBl[lo] = *(const bf16x8*)&Bgl[gb];
    }
    __syncthreads();
    bf16x8 a_h[4], a_l[4], b_h[4], b_l[4];
#pragma unroll
    for (int m = 0; m < 4; ++m) {
      int ra = (wr + m * 16 + l15) * LDT + l4 * 8;
      a_h[m] = *(const bf16x8*)&sAh[ra];
      a_l[m] = *(const bf16x8*)&sAl[ra];
      int rb = (wc + m * 16 + l15) * LDT + l4 * 8;
      b_h[m] = *(const bf16x8*)&sBh[rb];
      b_l[m] = *(const bf16x8*)&sBl[rb];
    }
#pragma unroll
    for (int m = 0; m < 4; ++m)
#pragma unroll
      for (int n = 0; n < 4; ++n) {
        acc[m][n] = __builtin_amdgcn_mfma_f32_16x16x32_bf16(a_h[m], b_h[n], acc[m][n], 0, 0, 0);
        acc[m][n] = __builtin_amdgcn_mfma_f32_16x16x32_bf16(a_h[m], b_l[n], acc[m][n], 0, 0, 0);
        acc[m][n] = __builtin_amdgcn_mfma_f32_16x16x32_bf16(a_l[m], b_h[n], acc[m][n], 0, 0, 0);
      }
  }
  // epilogue: C/D frag layout col = lane&15, row = (lane>>4)*4 + j  [m89/m91]
#pragma unroll
  for (int m = 0; m < 4; ++m)
#pragma unroll
    for (int n = 0; n < 4; ++n) {
      int row0 = bm * 128 + wr + m * 16 + l4 * 4;
      int col = bn * 128 + wc + n * 16 + l15;
      float bv = 0.f;
      if constexpr (EPI == 1) bv = bias[col];
#pragma unroll
      for (int j = 0; j < 4; ++j) {
        size_t idx = (size_t)(row0 + j) * HDIM + col;
        float v = acc[m][n][j];
        if constexpr (EPI == 0) {
          bf16_t hb = (bf16_t)v;
          Ch[idx] = hb;
          Cl[idx] = (bf16_t)(v - (float)hb);
        } else {
          Cf[idx] = v + bv;
        }
      }
    }
}

// ---------------- fused attention ----------------
// One block per (b,h,s): S[q][t] = scale*Q.Kv^T + mask*-1e4; softmax over t;
// O[q][d] = P Kv. 4 waves, each owns 16 q-rows. All LDS tiles padded to 72.
__global__ __launch_bounds__(256) void attn_kernel(
    const bf16_t* __restrict__ qh, const bf16_t* __restrict__ ql,
    const bf16_t* __restrict__ kvh, const bf16_t* __restrict__ kvl,
    const float* __restrict__ mask,
    bf16_t* __restrict__ resh, bf16_t* __restrict__ resl) {
  const int s = blockIdx.x, hh = blockIdx.y, b = blockIdx.z;
  const int tid = threadIdx.x, lane = tid & 63, w = tid >> 6;
  const int l15 = lane & 15, l4 = lane >> 4;
  const int LDT = 72;
  __shared__ bf16_t Qh[64 * 72], Ql[64 * 72];  // [q][d]
  __shared__ bf16_t Kh[64 * 72], Kl[64 * 72];  // [t][d]
  __shared__ bf16_t Th[64 * 72], Tl[64 * 72];  // [d][t] (KV^T for PV B-operand)
  __shared__ bf16_t Ph[64 * 72], Pl[64 * 72];  // alpha [q][t]
  __shared__ float mk[64];

  if (tid < 64) mk[tid] = mask[(size_t)(b * 64 + s) * 64 + tid];
#pragma unroll
  for (int j = 0; j < 2; ++j) {
    int c = tid + j * 256;  // 64 rows x 8 chunks
    int row = c >> 3, cg = c & 7;
    size_t gq = (size_t)(b * 64 + row) * HDIM + hh * 64 + cg * 8;
    size_t gk = (size_t)((b * 64 + s) * 64 + row) * HDIM + hh * 64 + cg * 8;
    bf16x8 vh = *(const bf16x8*)&qh[gq];
    bf16x8 vl = *(const bf16x8*)&ql[gq];
    *(bf16x8*)&Qh[row * LDT + cg * 8] = vh;
    *(bf16x8*)&Ql[row * LDT + cg * 8] = vl;
    bf16x8 kh8 = *(const bf16x8*)&kvh[gk];
    bf16x8 kl8 = *(const bf16x8*)&kvl[gk];
    *(bf16x8*)&Kh[row * LDT + cg * 8] = kh8;
    *(bf16x8*)&Kl[row * LDT + cg * 8] = kl8;
#pragma unroll
    for (int e = 0; e < 8; ++e) {  // transpose into Th/Tl
      Th[(cg * 8 + e) * LDT + row] = kh8[e];
      Tl[(cg * 8 + e) * LDT + row] = kl8[e];
    }
  }
  __syncthreads();

  // ---- scores: S = Q @ KV^T (A rows from Qh, B "[col][k]" rows from Kh) ----
  f32x4 S[4] = {};
#pragma unroll
  for (int ks = 0; ks < 2; ++ks) {
    int kc = ks * 4 + l4;
    int ar = (w * 16 + l15) * LDT + kc * 8;
    bf16x8 ah = *(const bf16x8*)&Qh[ar];
    bf16x8 al = *(const bf16x8*)&Ql[ar];
#pragma unroll
    for (int n = 0; n < 4; ++n) {
      int br = (n * 16 + l15) * LDT + kc * 8;
      bf16x8 bh8 = *(const bf16x8*)&Kh[br];
      bf16x8 bl8 = *(const bf16x8*)&Kl[br];
      S[n] = __builtin_amdgcn_mfma_f32_16x16x32_bf16(ah, bh8, S[n], 0, 0, 0);
      S[n] = __builtin_amdgcn_mfma_f32_16x16x32_bf16(ah, bl8, S[n], 0, 0, 0);
      S[n] = __builtin_amdgcn_mfma_f32_16x16x32_bf16(al, bh8, S[n], 0, 0, 0);
    }
  }
  const float scale = 0.125f;  // 1/sqrt(64)
  float mv[4];
#pragma unroll
  for (int n = 0; n < 4; ++n) mv[n] = mk[n * 16 + l15] * -10000.0f;
#pragma unroll
  for (int n = 0; n < 4; ++n)
#pragma unroll
    for (int j = 0; j < 4; ++j) S[n][j] = S[n][j] * scale + mv[n];

  // ---- softmax over t; row (q) = (lane>>4)*4 + j, 16 lanes/group hold 64 t ----
#pragma unroll
  for (int j = 0; j < 4; ++j) {
    float m0 = fmaxf(fmaxf(S[0][j], S[1][j]), fmaxf(S[2][j], S[3][j]));
    m0 = fmaxf(m0, __shfl_xor(m0, 1));
    m0 = fmaxf(m0, __shfl_xor(m0, 2));
    m0 = fmaxf(m0, __shfl_xor(m0, 4));
    m0 = fmaxf(m0, __shfl_xor(m0, 8));
    float sum = 0.f;
#pragma unroll
    for (int n = 0; n < 4; ++n) {
      float e = __expf(S[n][j] - m0);
      S[n][j] = e;
      sum += e;
    }
    sum += __shfl_xor(sum, 1);
    sum += __shfl_xor(sum, 2);
    sum += __shfl_xor(sum, 4);
    sum += __shfl_xor(sum, 8);
    float inv = 1.0f / sum;
#pragma unroll
    for (int n = 0; n < 4; ++n) S[n][j] *= inv;
  }

  // ---- P -> LDS (lane-transpose via memory); wave reads only its own rows ----
#pragma unroll
  for (int n = 0; n < 4; ++n)
#pragma unroll
    for (int j = 0; j < 4; ++j) {
      int q = w * 16 + l4 * 4 + j;
      int t = n * 16 + l15;
      float a = S[n][j];
      bf16_t hb = (bf16_t)a;
      Ph[q * LDT + t] = hb;
      Pl[q * LDT + t] = (bf16_t)(a - (float)hb);
    }

  // ---- PV: O = P @ KV  (B "[col=d][k=t]" rows from Th) ----
  f32x4 O[4] = {};
#pragma unroll
  for (int ks = 0; ks < 2; ++ks) {
    int kc = ks * 4 + l4;
    int ar = (w * 16 + l15) * LDT + kc * 8;
    bf16x8 ph = *(const bf16x8*)&Ph[ar];
    bf16x8 pl = *(const bf16x8*)&Pl[ar];
#pragma unroll
    for (int n = 0; n < 4; ++n) {
      int br = (n * 16 + l15) * LDT + kc * 8;
      bf16x8 th8 = *(const bf16x8*)&Th[br];
      bf16x8 tl8 = *(const bf16x8*)&Tl[br];
      O[n] = __builtin_amdgcn_mfma_f32_16x16x32_bf16(ph, th8, O[n], 0, 0, 0);
      O[n] = __builtin_amdgcn_mfma_f32_16x16x32_bf16(ph, tl8, O[n], 0, 0, 0);
      O[n] = __builtin_amdgcn_mfma_f32_16x16x32_bf16(pl, th8, O[n], 0, 0, 0);
    }
  }

  // ---- res[b,q,s, h*64+d] hi/lo ----
#pragma unroll
  for (int n = 0; n < 4; ++n)
#pragma unroll
    for (int j = 0; j < 4; ++j) {
      int q = w * 16 + l4 * 4 + j;
      size_t idx = ((size_t)((b * 64 + q) * 64 + s)) * HDIM + hh * 64 + n * 16 + l15;
      float v = O[n][j];
      bf16_t hb = (bf16_t)v;
      resh[idx] = hb;
      resl[idx] = (bf16_t)(v - (float)hb);
    }
}

// ---------------- launch ----------------
extern "C" void kernel_launch(void* const* d_in, const int* in_sizes, int n_in,
                              void* d_out, int out_size, void* d_ws, size_t ws_size,
                              hipStream_t stream) {
  const float* ini_q = (const float*)d_in[0];
  const float* ini_k = (const float*)d_in[1];
  const float* mask = (const float*)d_in[2];
  const float* Wq = (const float*)d_in[3];
  const float* Wkv = (const float*)d_in[4];
  const float* Wo = (const float*)d_in[5];
  const float* bo = (const float*)d_in[6];
  float* out = (float*)d_out;

  const size_t SQ = 512ull * HDIM;    // 393216
  const size_t SK = 32768ull * HDIM;  // 25165824
  const size_t SW = 768ull * HDIM;    // 589824

  char* p = (char*)d_ws;
  auto carve = [&](size_t bytes) {
    char* r = p;
    p += (bytes + 255) & ~(size_t)255;
    return r;
  };
  bf16_t* iq_h = (bf16_t*)carve(SQ * 2);
  bf16_t* iq_l = (bf16_t*)carve(SQ * 2);
  bf16_t* ik_h = (bf16_t*)carve(SK * 2);
  bf16_t* ik_l = (bf16_t*)carve(SK * 2);
  bf16_t* wq_h = (bf16_t*)carve(SW * 2);
  bf16_t* wq_l = (bf16_t*)carve(SW * 2);
  bf16_t* wkv_h = (bf16_t*)carve(SW * 2);
  bf16_t* wkv_l = (bf16_t*)carve(SW * 2);
  bf16_t* wo_h = (bf16_t*)carve(SW * 2);
  bf16_t* wo_l = (bf16_t*)carve(SW * 2);
  bf16_t* q_h = (bf16_t*)carve(SQ * 2);
  bf16_t* q_l = (bf16_t*)carve(SQ * 2);
  bf16_t* kv_h = (bf16_t*)carve(SK * 2);
  bf16_t* kv_l = (bf16_t*)carve(SK * 2);
  // res reuses ini_k split buffers (dead after the kv GEMM)
  bf16_t* res_h = ik_h;
  bf16_t* res_l = ik_l;
  if ((size_t)(p - (char*)d_ws) > ws_size) return;  // ws too small: fail visibly

  split4_kernel<<<dim3(SQ / 4 / 256), 256, 0, stream>>>(ini_q, iq_h, iq_l);
  split4_kernel<<<dim3(SK / 4 / 256), 256, 0, stream>>>(ini_k, ik_h, ik_l);
  splitT_kernel<<<dim3(SW / 256), 256, 0, stream>>>(Wq, wq_h, wq_l);
  splitT_kernel<<<dim3(SW / 256), 256, 0, stream>>>(Wkv, wkv_h, wkv_l);
  splitT_kernel<<<dim3(SW / 256), 256, 0, stream>>>(Wo, wo_h, wo_l);

  // q = ini_q @ Wq
  gemm_kernel<0><<<dim3(6, 4), 256, 0, stream>>>(iq_h, iq_l, wq_h, wq_l,
                                                 q_h, q_l, nullptr, nullptr);
  // kv = ini_k @ Wkv
  gemm_kernel<0><<<dim3(6, 256), 256, 0, stream>>>(ik_h, ik_l, wkv_h, wkv_l,
                                                   kv_h, kv_l, nullptr, nullptr);
  // attention
  attn_kernel<<<dim3(64, 12, 8), 256, 0, stream>>>(q_h, q_l, kv_h, kv_l, mask,
                                                   res_h, res_l);
  // out = res @ Wo + bo
  gemm_kernel<1><<<dim3(6, 256), 256, 0, stream>>>(res_h, res_l, wo_h, wo_l,
                                                   nullptr, nullptr, out, bo);
}

// Round 2
// 541.921 us; speedup vs baseline: 1.1182x; 1.1182x over previous
//
#include <hip/hip_runtime.h>
#include <stdint.h>

// MHATokenNoLayerNorm on MI355X (gfx950).
// fp32 -> (bf16 hi, bf16 lo) split; all GEMM-shaped ops use
// mfma_f32_16x16x32_bf16 with 3-term split product (hh + hl + lh).
// Pipeline:
//   splitT(Wq/Wkv/Wo)                      (weights pre-split+transposed)
//   gemm<AF32>: q   = ini_q @ Wq           (512 x 768 x 768), split on the fly
//   gemm<AF32>: kvT = (ini_k @ Wkv)^T      (32768 x 768 x 768) -> [b,s,h][d][t]
//   attn per (b,h,s): S^T = K Q^T, softmax over t, O^T = kvT P^T -> res hi/lo
//   gemm<gload>: out = res @ Wo + bo       (32768 x 768 x 768)
// GEMM: 128x128 tile, BK=32, global_load_lds width-16, XCD-chunked swizzle.

typedef __bf16 bf16_t;
typedef __attribute__((ext_vector_type(8))) __bf16 bf16x8;
typedef __attribute__((ext_vector_type(4))) __bf16 bf16x4;
typedef __attribute__((ext_vector_type(4))) float f32x4;

#define HDIM 768

__device__ __forceinline__ void gload16(const bf16_t* g, bf16_t* l) {
  __builtin_amdgcn_global_load_lds(
      (const __attribute__((address_space(1))) void*)g,
      (__attribute__((address_space(3))) void*)l, 16, 0, 0);
}

// ---------------- weight split+transpose ----------------
__global__ __launch_bounds__(256) void splitT_kernel(const float* __restrict__ w,
                                                     bf16_t* __restrict__ hT,
                                                     bf16_t* __restrict__ lT) {
  int idx = blockIdx.x * 256 + threadIdx.x;  // 589824 threads
  int k = idx / HDIM, n = idx % HDIM;
  float v = w[idx];
  bf16_t hb = (bf16_t)v;
  hT[n * HDIM + k] = hb;
  lT[n * HDIM + k] = (bf16_t)(v - (float)hb);
}

// ---------------- split-bf16 GEMM ----------------
// C[M,768] = A[M,768] @ W[768,768]; W transposed+pre-split (WT[n][k] hi/lo).
// AF32: A staged from fp32 global with on-the-fly hi/lo split (reg->LDS).
// else: A staged from pre-split bf16 hi/lo via global_load_lds.
// EPI 0: C -> natural bf16 hi/lo. EPI 1: C -> f32 + bias.
// EPI 2: C -> ONLY transposed kvT layout [b,s,h][d][t] hi/lo (b64 stores).
template <int EPI, bool AF32>
__global__ __launch_bounds__(256) void gemm_kernel(
    const float* __restrict__ Agf,
    const bf16_t* __restrict__ Agh, const bf16_t* __restrict__ Agl,
    const bf16_t* __restrict__ Bgh, const bf16_t* __restrict__ Bgl,
    bf16_t* __restrict__ Ch, bf16_t* __restrict__ Cl,
    bf16_t* __restrict__ CTh, bf16_t* __restrict__ CTl,
    float* __restrict__ Cf, const float* __restrict__ bias) {
  __shared__ bf16_t sAh[128 * 32], sAl[128 * 32], sBh[128 * 32], sBl[128 * 32];
  // XCD-chunked swizzle (nwg % 8 == 0 always here): consecutive logical tiles
  // (sharing an A panel, bn fastest) land on one XCD's L2.
  const int nwg = gridDim.x;
  const int cpx = nwg >> 3;
  const int g = blockIdx.x;
  const int wg = (g & 7) * cpx + (g >> 3);
  const int bn = wg % 6, bm = wg / 6;
  const int tid = threadIdx.x, lane = tid & 63, w = tid >> 6;
  const int wr = (w >> 1) * 64, wc = (w & 1) * 64;
  const int l15 = lane & 15, l4 = lane >> 4;
  f32x4 acc[4][4] = {};

  for (int kt = 0; kt < 24; ++kt) {
    const int k0 = kt * 32;
    __syncthreads();
    if constexpr (AF32) {
      // A tile 128x32 f32 = 1024 chunks of 4 f32; split to hi/lo in regs.
#pragma unroll
      for (int j = 0; j < 4; ++j) {
        const int c = tid + j * 256;
        const int row = c >> 3, cg = c & 7;
        const float4 v4 =
            *(const float4*)&Agf[(size_t)(bm * 128 + row) * HDIM + k0 + cg * 4];
        const float vv[4] = {v4.x, v4.y, v4.z, v4.w};
        bf16x4 hv, lv;
#pragma unroll
        for (int e = 0; e < 4; ++e) {
          bf16_t hb = (bf16_t)vv[e];
          hv[e] = hb;
          lv[e] = (bf16_t)(vv[e] - (float)hb);
        }
        *(bf16x4*)&sAh[row * 32 + cg * 4] = hv;
        *(bf16x4*)&sAl[row * 32 + cg * 4] = lv;
      }
    } else {
#pragma unroll
      for (int j = 0; j < 2; ++j) {
        const int c0 = j * 256 + w * 64;  // wave-uniform chunk base
        const int c = c0 + lane;
        const int row = c >> 2, cg = c & 3;
        const size_t ga = (size_t)(bm * 128 + row) * HDIM + k0 + cg * 8;
        gload16(&Agh[ga], &sAh[c0 * 8]);
        gload16(&Agl[ga], &sAl[c0 * 8]);
      }
    }
#pragma unroll
    for (int j = 0; j < 2; ++j) {
      const int c0 = j * 256 + w * 64;
      const int c = c0 + lane;
      const int row = c >> 2, cg = c & 3;
      const size_t gb = (size_t)(bn * 128 + row) * HDIM + k0 + cg * 8;
      gload16(&Bgh[gb], &sBh[c0 * 8]);
      gload16(&Bgl[gb], &sBl[c0 * 8]);
    }
    __syncthreads();
    bf16x8 a_h[4], a_l[4], b_h[4], b_l[4];
#pragma unroll
    for (int m = 0; m < 4; ++m) {
      const int ra = (wr + m * 16 + l15) * 32 + l4 * 8;
      a_h[m] = *(const bf16x8*)&sAh[ra];
      a_l[m] = *(const bf16x8*)&sAl[ra];
      const int rb = (wc + m * 16 + l15) * 32 + l4 * 8;
      b_h[m] = *(const bf16x8*)&sBh[rb];
      b_l[m] = *(const bf16x8*)&sBl[rb];
    }
#pragma unroll
    for (int m = 0; m < 4; ++m)
#pragma unroll
      for (int n = 0; n < 4; ++n) {
        acc[m][n] = __builtin_amdgcn_mfma_f32_16x16x32_bf16(a_h[m], b_h[n], acc[m][n], 0, 0, 0);
        acc[m][n] = __builtin_amdgcn_mfma_f32_16x16x32_bf16(a_h[m], b_l[n], acc[m][n], 0, 0, 0);
        acc[m][n] = __builtin_amdgcn_mfma_f32_16x16x32_bf16(a_l[m], b_h[n], acc[m][n], 0, 0, 0);
      }
  }
  // epilogue: C/D frag layout col = lane&15, row = (lane>>4)*4 + j
#pragma unroll
  for (int m = 0; m < 4; ++m)
#pragma unroll
    for (int n = 0; n < 4; ++n) {
      const int row0 = bm * 128 + wr + m * 16 + l4 * 4;
      const int col = bn * 128 + wc + n * 16 + l15;
      if constexpr (EPI == 1) {
        const float bv = bias[col];
#pragma unroll
        for (int j = 0; j < 4; ++j)
          Cf[(size_t)(row0 + j) * HDIM + col] = acc[m][n][j] + bv;
      } else if constexpr (EPI == 0) {
#pragma unroll
        for (int j = 0; j < 4; ++j) {
          const float v = acc[m][n][j];
          const bf16_t hb = (bf16_t)v;
          Ch[(size_t)(row0 + j) * HDIM + col] = hb;
          Cl[(size_t)(row0 + j) * HDIM + col] = (bf16_t)(v - (float)hb);
        }
      } else {  // EPI == 2: kvT only, [b,s,h][d][t], t contiguous -> b64 stores
        bf16x4 hv, lv;
#pragma unroll
        for (int j = 0; j < 4; ++j) {
          const float v = acc[m][n][j];
          const bf16_t hb = (bf16_t)v;
          hv[j] = hb;
          lv[j] = (bf16_t)(v - (float)hb);
        }
        const int b = row0 >> 12, s = (row0 >> 6) & 63, t0 = row0 & 63;
        const int hh = col >> 6, d = col & 63;
        const size_t tb =
            ((size_t)((b * 64 + s) * 12 + hh)) * 4096 + d * 64 + t0;
        *(bf16x4*)&CTh[tb] = hv;
        *(bf16x4*)&CTl[tb] = lv;
      }
    }
}

// ---------------- fused attention ----------------
// One block per (b,h,s), 4 waves. Swapped QK^T: S^T[t][q] = mfma(A=K, B=Q),
// softmax over t is lane-local (16 vals) + 2 shuffles. P stored [q][t] with
// b64 stores. PV: O^T[d][q] = mfma(A=kvT rows (global), B=P rows (LDS)).
// res written coalesced via f32 LDS bounce (overlays dead K buffer).
__global__ __launch_bounds__(256) void attn_kernel(
    const bf16_t* __restrict__ qh, const bf16_t* __restrict__ ql,
    const bf16_t* __restrict__ kvTh, const bf16_t* __restrict__ kvTl,
    const float* __restrict__ mask,
    bf16_t* __restrict__ resh, bf16_t* __restrict__ resl) {
  const int s = blockIdx.x, hh = blockIdx.y, b = blockIdx.z;
  const int tid = threadIdx.x, lane = tid & 63, w = tid >> 6;
  const int l15 = lane & 15, l4 = lane >> 4;
  const int LDT = 72, LDP = 68;
  __shared__ __align__(16) char smemA[64 * 72 * 2 * 2];  // Kh,Kl | later OldsF
  __shared__ __align__(16) bf16_t Ph[64 * 72], Pl[64 * 72];
  __shared__ float mk[64];
  bf16_t* Kh = (bf16_t*)smemA;
  bf16_t* Kl = Kh + 64 * 72;
  float* OldsF = (float*)smemA;  // overlays K (dead after QK^T phase)

  if (tid < 64) mk[tid] = mask[((size_t)b * 64 + s) * 64 + tid] * -10000.0f;

  const size_t tb0 = ((size_t)((b * 64 + s) * 12 + hh)) * 4096;
  // restore K[t][d] from kvT[d][t]; lane=d => conflict-free scalar LDS writes
#pragma unroll
  for (int j = 0; j < 2; ++j) {
    const int cg = j * 4 + w;  // wave-uniform t-chunk
    const bf16x8 vh = *(const bf16x8*)&kvTh[tb0 + (size_t)lane * 64 + cg * 8];
    const bf16x8 vl = *(const bf16x8*)&kvTl[tb0 + (size_t)lane * 64 + cg * 8];
#pragma unroll
    for (int e = 0; e < 8; ++e) {
      Kh[(cg * 8 + e) * LDT + lane] = vh[e];
      Kl[(cg * 8 + e) * LDT + lane] = vl[e];
    }
  }

  // Q fragments direct from global (B-operand: col q = w*16+l15)
  const size_t qbase = ((size_t)(b * 64 + w * 16 + l15)) * HDIM + hh * 64;
  bf16x8 qh8[2], ql8[2];
#pragma unroll
  for (int ks = 0; ks < 2; ++ks) {
    qh8[ks] = *(const bf16x8*)&qh[qbase + ks * 32 + l4 * 8];
    ql8[ks] = *(const bf16x8*)&ql[qbase + ks * 32 + l4 * 8];
  }
  __syncthreads();

  // ---- S^T[t][q]: A = K rows [t][d] (LDS), B = Q rows [q][d] (regs) ----
  f32x4 St[4] = {};
#pragma unroll
  for (int ks = 0; ks < 2; ++ks) {
#pragma unroll
    for (int mf = 0; mf < 4; ++mf) {
      const int ra = (mf * 16 + l15) * LDT + ks * 32 + l4 * 8;
      const bf16x8 kh8 = *(const bf16x8*)&Kh[ra];
      const bf16x8 kl8 = *(const bf16x8*)&Kl[ra];
      St[mf] = __builtin_amdgcn_mfma_f32_16x16x32_bf16(kh8, qh8[ks], St[mf], 0, 0, 0);
      St[mf] = __builtin_amdgcn_mfma_f32_16x16x32_bf16(kh8, ql8[ks], St[mf], 0, 0, 0);
      St[mf] = __builtin_amdgcn_mfma_f32_16x16x32_bf16(kl8, qh8[ks], St[mf], 0, 0, 0);
    }
  }

  // ---- softmax over t: per-lane 16 vals (t = mf*16 + l4*4 + j), q = w*16+l15
  float p[16];
  float mx = -1e30f;
#pragma unroll
  for (int mf = 0; mf < 4; ++mf)
#pragma unroll
    for (int j = 0; j < 4; ++j) {
      const float v = St[mf][j] * 0.125f + mk[mf * 16 + l4 * 4 + j];
      p[mf * 4 + j] = v;
      mx = fmaxf(mx, v);
    }
  mx = fmaxf(mx, __shfl_xor(mx, 16));
  mx = fmaxf(mx, __shfl_xor(mx, 32));
  float sum = 0.f;
#pragma unroll
  for (int i = 0; i < 16; ++i) {
    const float e = __expf(p[i] - mx);
    p[i] = e;
    sum += e;
  }
  sum += __shfl_xor(sum, 16);
  sum += __shfl_xor(sum, 32);
  const float inv = 1.0f / sum;

  // ---- P[q][t] hi/lo, b64 stores (j contiguous in t) ----
  const int q = w * 16 + l15;
#pragma unroll
  for (int mf = 0; mf < 4; ++mf) {
    bf16x4 hv, lv;
#pragma unroll
    for (int j = 0; j < 4; ++j) {
      const float v = p[mf * 4 + j] * inv;
      const bf16_t hb = (bf16_t)v;
      hv[j] = hb;
      lv[j] = (bf16_t)(v - (float)hb);
    }
    *(bf16x4*)&Ph[q * LDT + mf * 16 + l4 * 4] = hv;
    *(bf16x4*)&Pl[q * LDT + mf * 16 + l4 * 4] = lv;
  }
  __syncthreads();

  // ---- O^T[d][q] = mfma(A = kvT rows d=w*16+l15 (global), B = P rows (LDS))
  f32x4 Ot[4] = {};
  const size_t ab = tb0 + (size_t)(w * 16 + l15) * 64;
#pragma unroll
  for (int ks = 0; ks < 2; ++ks) {
    const bf16x8 ah = *(const bf16x8*)&kvTh[ab + ks * 32 + l4 * 8];
    const bf16x8 al = *(const bf16x8*)&kvTl[ab + ks * 32 + l4 * 8];
#pragma unroll
    for (int nf = 0; nf < 4; ++nf) {
      const int rb = (nf * 16 + l15) * LDT + ks * 32 + l4 * 8;
      const bf16x8 ph8 = *(const bf16x8*)&Ph[rb];
      const bf16x8 pl8 = *(const bf16x8*)&Pl[rb];
      Ot[nf] = __builtin_amdgcn_mfma_f32_16x16x32_bf16(ah, ph8, Ot[nf], 0, 0, 0);
      Ot[nf] = __builtin_amdgcn_mfma_f32_16x16x32_bf16(ah, pl8, Ot[nf], 0, 0, 0);
      Ot[nf] = __builtin_amdgcn_mfma_f32_16x16x32_bf16(al, ph8, Ot[nf], 0, 0, 0);
    }
  }
  // O frag: row d = w*16 + l4*4 + j, col q = nf*16 + l15 -> bounce [q][d] f32
#pragma unroll
  for (int nf = 0; nf < 4; ++nf)
    *(f32x4*)&OldsF[(nf * 16 + l15) * LDP + w * 16 + l4 * 4] = Ot[nf];
  __syncthreads();

  // ---- res[b,q,s][hh*64+d] hi/lo, coalesced bf16x8 stores ----
  const int qq = tid >> 2, ch = tid & 3;
  float vv[16];
#pragma unroll
  for (int k = 0; k < 4; ++k) {
    const f32x4 t4 = *(const f32x4*)&OldsF[qq * LDP + ch * 16 + k * 4];
    vv[k * 4 + 0] = t4[0]; vv[k * 4 + 1] = t4[1];
    vv[k * 4 + 2] = t4[2]; vv[k * 4 + 3] = t4[3];
  }
  bf16x8 h8[2], l8[2];
#pragma unroll
  for (int k = 0; k < 16; ++k) {
    const float v = vv[k];
    const bf16_t hb = (bf16_t)v;
    h8[k >> 3][k & 7] = hb;
    l8[k >> 3][k & 7] = (bf16_t)(v - (float)hb);
  }
  const size_t rb = ((size_t)((b * 64 + qq) * 64 + s)) * HDIM + hh * 64 + ch * 16;
  *(bf16x8*)&resh[rb] = h8[0];
  *(bf16x8*)&resh[rb + 8] = h8[1];
  *(bf16x8*)&resl[rb] = l8[0];
  *(bf16x8*)&resl[rb + 8] = l8[1];
}

// ---------------- launch ----------------
extern "C" void kernel_launch(void* const* d_in, const int* in_sizes, int n_in,
                              void* d_out, int out_size, void* d_ws, size_t ws_size,
                              hipStream_t stream) {
  const float* ini_q = (const float*)d_in[0];
  const float* ini_k = (const float*)d_in[1];
  const float* mask = (const float*)d_in[2];
  const float* Wq = (const float*)d_in[3];
  const float* Wkv = (const float*)d_in[4];
  const float* Wo = (const float*)d_in[5];
  const float* bo = (const float*)d_in[6];
  float* out = (float*)d_out;

  const size_t SQ = 512ull * HDIM;    // 393216
  const size_t SK = 32768ull * HDIM;  // 25165824
  const size_t SW = 768ull * HDIM;    // 589824

  char* p = (char*)d_ws;
  auto carve = [&](size_t bytes) {
    char* r = p;
    p += (bytes + 255) & ~(size_t)255;
    return r;
  };
  bf16_t* wq_h = (bf16_t*)carve(SW * 2);
  bf16_t* wq_l = (bf16_t*)carve(SW * 2);
  bf16_t* wkv_h = (bf16_t*)carve(SW * 2);
  bf16_t* wkv_l = (bf16_t*)carve(SW * 2);
  bf16_t* wo_h = (bf16_t*)carve(SW * 2);
  bf16_t* wo_l = (bf16_t*)carve(SW * 2);
  bf16_t* q_h = (bf16_t*)carve(SQ * 2);
  bf16_t* q_l = (bf16_t*)carve(SQ * 2);
  bf16_t* kvT_h = (bf16_t*)carve(SK * 2);
  bf16_t* kvT_l = (bf16_t*)carve(SK * 2);
  bf16_t* res_h = (bf16_t*)carve(SK * 2);
  bf16_t* res_l = (bf16_t*)carve(SK * 2);
  if ((size_t)(p - (char*)d_ws) > ws_size) return;  // ws too small: fail visibly

  splitT_kernel<<<dim3(SW / 256), 256, 0, stream>>>(Wq, wq_h, wq_l);
  splitT_kernel<<<dim3(SW / 256), 256, 0, stream>>>(Wkv, wkv_h, wkv_l);
  splitT_kernel<<<dim3(SW / 256), 256, 0, stream>>>(Wo, wo_h, wo_l);

  // q = ini_q @ Wq (natural hi/lo out)
  gemm_kernel<0, true><<<dim3(24), 256, 0, stream>>>(
      ini_q, nullptr, nullptr, wq_h, wq_l, q_h, q_l, nullptr, nullptr,
      nullptr, nullptr);
  // kvT = (ini_k @ Wkv)^T  [b,s,h][d][t]
  gemm_kernel<2, true><<<dim3(1536), 256, 0, stream>>>(
      ini_k, nullptr, nullptr, wkv_h, wkv_l, nullptr, nullptr, kvT_h, kvT_l,
      nullptr, nullptr);
  // attention
  attn_kernel<<<dim3(64, 12, 8), 256, 0, stream>>>(q_h, q_l, kvT_h, kvT_l,
                                                   mask, res_h, res_l);
  // out = res @ Wo + bo
  gemm_kernel<1, false><<<dim3(1536), 256, 0, stream>>>(
      nullptr, res_h, res_l, wo_h, wo_l, nullptr, nullptr, nullptr, nullptr,
      out, bo);
}